// Round 12
// baseline (6091.862 us; speedup 1.0000x reference)
//
#include <hip/hip_runtime.h>

#define B_ 64
#define S_ 512
#define H_ 512

typedef unsigned short u16;
typedef unsigned int   u32;
typedef unsigned long long u64;

typedef __attribute__((ext_vector_type(8))) short    bf16x8;
typedef __attribute__((ext_vector_type(8))) _Float16 f16x8;
typedef __attribute__((ext_vector_type(4))) float    f32x4;
typedef __attribute__((ext_vector_type(2))) _Float16 h2_t;

#define PJ_GATE ((size_t)512 * 64 * 512)   // P stride per gate: [512 ts][64 b][512 j]
#define TMASK 0xffff0000ffff0000ull

// ---------- helpers ----------
__device__ inline u16 f2bf(float f) {            // RNE fp32 -> bf16 bits
  u32 u = __builtin_bit_cast(u32, f);
  u32 r = (u + 0x7fffu + ((u >> 16) & 1u)) >> 16;
  return (u16)r;
}
__device__ inline u32 pkbf2(float a, float b) {
  return (u32)f2bf(a) | ((u32)f2bf(b) << 16);
}
__device__ inline u16 f2h(float a) {
  _Float16 x = (_Float16)a;
  return __builtin_bit_cast(u16, x);
}
__device__ inline u32 pk2h(float a, float b) {
  return (u32)f2h(a) | ((u32)f2h(b) << 16);
}
__device__ inline float sigmoidf_(float x) { return 1.f / (1.f + __expf(-x)); }
__device__ inline float tanhf_(float x) {
  float e = __expf(-2.f * fabsf(x));
  float t = (1.f - e) / (1.f + e);
  return copysignf(t, x);
}
__device__ inline void xstore64(u64* p, u64 v) {
  __hip_atomic_store(p, v, __ATOMIC_RELAXED, __HIP_MEMORY_SCOPE_AGENT);
}
__device__ inline u64 xload(const u64* p) {
  return __hip_atomic_load(p, __ATOMIC_RELAXED, __HIP_MEMORY_SCOPE_AGENT);
}
// publish 4 f32 as tagged f16 u32 slots (2 x u64)
__device__ inline void pub4(u32* gp, u32 taghi, f32x4 v) {
  u64 a = (u64)(taghi | f2h(v[0])) | ((u64)(taghi | f2h(v[1])) << 32);
  u64 b = (u64)(taghi | f2h(v[2])) | ((u64)(taghi | f2h(v[3])) << 32);
  xstore64((u64*)gp, a);
  xstore64((u64*)(gp + 2), b);
}
// poll 8 contiguous u64 tagged slots; pack 16 f16 into LDS (2 x uint4)
__device__ inline void poll8_to_lds(const u32* gbase, u16* lbase, u64 tp) {
  const u64* p = (const u64*)gbase;
  u64 v[8];
#pragma unroll
  for (int i = 0; i < 8; ++i) v[i] = xload(p + i);
#pragma unroll
  for (int i = 0; i < 8; ++i)
    while ((v[i] ^ tp) & TMASK) { __builtin_amdgcn_s_sleep(1); v[i] = xload(p + i); }
  u32 pk[8];
#pragma unroll
  for (int i = 0; i < 8; ++i)
    pk[i] = (u32)(v[i] & 0xffffu) | (((u32)(v[i] >> 32)) << 16);
  uint4 a = {pk[0], pk[1], pk[2], pk[3]};
  uint4 b = {pk[4], pk[5], pk[6], pk[7]};
  *(uint4*)(lbase) = a;
  *(uint4*)(lbase + 8) = b;
}

// ---------- kernel 1: W recurrent half -> f16 MFMA A-fragments ----------
// WF[g][rt][kt][lane] (uint4): 8 f16 = W_g[rt*16+(lane&15)][512 + kt*32 + (lane>>4)*8 + 0..7]
__global__ void k_convert_w(const float* __restrict__ Wr, const float* __restrict__ Wz,
                            const float* __restrict__ Wh, uint4* __restrict__ WF) {
  int g = blockIdx.y;
  const float* Ws = (g == 0) ? Wr : ((g == 1) ? Wz : Wh);
  int i = blockIdx.x * 256 + threadIdx.x;   // 0..32767
  int lane = i & 63;
  int kt   = (i >> 6) & 15;
  int rt   = i >> 10;                       // 0..31
  int row  = rt * 16 + (lane & 15);
  int col  = 512 + kt * 32 + (lane >> 4) * 8;
  const float* src = Ws + (size_t)row * 1024 + col;
  float4 a = *(const float4*)src;
  float4 b = *(const float4*)(src + 4);
  uint4 o;
  o.x = pk2h(a.x, a.y); o.y = pk2h(a.z, a.w);
  o.z = pk2h(b.x, b.y); o.w = pk2h(b.z, b.w);
  WF[((size_t)(g * 32 + rt) * 16 + kt) * 64 + lane] = o;
}

// ---------- kernel 2: projection GEMM (f32 in, bf16 MFMA, f16 out) ----------
__global__ __launch_bounds__(256) void k_proj_gemm(
    const float* __restrict__ x,
    const float* __restrict__ Wr, const float* __restrict__ Wz, const float* __restrict__ Wh,
    const float* __restrict__ br, const float* __restrict__ bz, const float* __restrict__ bh,
    u16* __restrict__ P)
{
  const int g  = blockIdx.z;
  const int bm = blockIdx.x * 64;
  const int bn = blockIdx.y * 64;
  const float* Ws = (g == 0) ? Wr : ((g == 1) ? Wz : Wh);
  __shared__ __align__(16) u16 As[64][32];
  __shared__ __align__(16) u16 Bs[64][32];
  const int tid  = threadIdx.x;
  const int lane = tid & 63;
  const int wm   = (tid >> 6) >> 1;
  const int wn   = (tid >> 6) & 1;
  const int srow = tid >> 2;
  const int scol = (tid & 3) * 8;

  f32x4 zero4 = {0.f, 0.f, 0.f, 0.f};
  f32x4 acc[2][2];
  acc[0][0] = zero4; acc[0][1] = zero4; acc[1][0] = zero4; acc[1][1] = zero4;

  for (int k0 = 0; k0 < 512; k0 += 32) {
    __syncthreads();
    {
      const float* xs = x + (size_t)(bm + srow) * 512 + k0 + scol;
      float4 a = *(const float4*)xs, b = *(const float4*)(xs + 4);
      uint4 av; av.x = pkbf2(a.x, a.y); av.y = pkbf2(a.z, a.w);
      av.z = pkbf2(b.x, b.y); av.w = pkbf2(b.z, b.w);
      *(uint4*)(&As[srow][scol]) = av;
      const float* wsrc = Ws + (size_t)(bn + srow) * 1024 + k0 + scol;
      float4 c = *(const float4*)wsrc, d = *(const float4*)(wsrc + 4);
      uint4 bv; bv.x = pkbf2(c.x, c.y); bv.y = pkbf2(c.z, c.w);
      bv.z = pkbf2(d.x, d.y); bv.w = pkbf2(d.z, d.w);
      *(uint4*)(&Bs[srow][scol]) = bv;
    }
    __syncthreads();
#pragma unroll
    for (int mi = 0; mi < 2; ++mi) {
      bf16x8 a = *(const bf16x8*)(&As[wm * 32 + mi * 16 + (lane & 15)][(lane >> 4) * 8]);
#pragma unroll
      for (int ni = 0; ni < 2; ++ni) {
        bf16x8 b = *(const bf16x8*)(&Bs[wn * 32 + ni * 16 + (lane & 15)][(lane >> 4) * 8]);
        acc[mi][ni] = __builtin_amdgcn_mfma_f32_16x16x32_bf16(a, b, acc[mi][ni], 0, 0, 0);
      }
    }
  }
  const float* bias = (g == 0) ? br : ((g == 1) ? bz : bh);
#pragma unroll
  for (int mi = 0; mi < 2; ++mi)
#pragma unroll
    for (int ni = 0; ni < 2; ++ni) {
      int col  = bn + wn * 32 + ni * 16 + (lane & 15);
      float bv = bias[col];
#pragma unroll
      for (int r = 0; r < 4; ++r) {
        int row = bm + wm * 32 + mi * 16 + (lane >> 4) * 4 + r;
        int bb = row >> 9, ss = row & 511;
        float v = acc[mi][ni][r] + bv;
        P[((size_t)g * 512 + ss) * (64 * 512) + (size_t)bb * 512 + col] =
            __builtin_bit_cast(u16, (_Float16)v);
      }
    }
}

// ---------- kernel 3: GRU scan — 16-block clusters, ALL W in LDS ----------
// 64 blocks x 512 thr. cluster c = blockIdx>>4 owns batches 16c..16c+15;
// block q = blockIdx&15 owns rows [32q, 32q+32) of ALL 3 gates; W slice =
// 96 KB, fully LDS-resident (no register residency needed, builtin MFMAs).
// Phase A (8 waves): (gate r/z) x (row-tile 0/1) x (k-half 0/1); k-half-1
//   partials staged in LDS, k-half-0 waves reduce + sigmoid. r-waves publish
//   tagged rh; z-waves write zbuf. Phase B: (row-tile) x (k-quarter); quarters
//   1-3 staged, quarter-0 waves reduce + tanh + gate + publish tagged h + y.
// Exchange = round-5 tag-in-word poll (relaxed agent atomics, parity dbuf,
// max skew 1 step by induction); polls cover all 512 rows uniformly.
__global__ __launch_bounds__(512) void k_gru_scan(
    const float* __restrict__ h0,
    const u16*  __restrict__ P,       // [3][512 ts][64 b][512 j] f16
    const uint4* __restrict__ WF,     // fragment-packed recurrent W (f16)
    u32* __restrict__ RHX,            // [2 par][4 c][16 b][512 j] tagged r*h
    u32* __restrict__ HX,             // [2 par][4 c][16 b][512 j] tagged h
    float* __restrict__ y,
    float* __restrict__ hlast)
{
  const int q = blockIdx.x & 15;
  const int c = blockIdx.x >> 4;
  const int t = threadIdx.x;
  const int w = t >> 6;          // wave 0..7
  const int l = t & 63;
  const int bq = l & 15;         // batch within cluster (MFMA col)
  const int g4 = l >> 4;         // 0..3
  const int bglob = c * 16 + bq;

  // phase-A role: gate gA (0=r,1=z), row-tile rtA, k-half khA
  const int gA  = w >> 2;
  const int rtA = (w >> 1) & 1;
  const int khA = w & 1;
  // phase-B role: row-tile rtB, k-quarter kqB
  const int rtB = w & 1;
  const int kqB = w >> 1;

  const int jA = q * 32 + rtA * 16 + g4 * 4;   // phase-A output rows (khA==0)
  const int jB = q * 32 + rtB * 16 + g4 * 4;   // phase-B output rows (kqB==0)

  __shared__ __align__(16) u16 whlds[49152];   // 96 KB [g 3][rt 2][kt 16][lane 64][8]
  __shared__ __align__(16) u16 hbuf[16 * 520];   // f16 h   [b][j], pad 8
  __shared__ __align__(16) u16 rhbuf[16 * 520];  // f16 r*h [b][j], pad 8
  __shared__ float zbuf[32][16];                 // z [local row][b]
  __shared__ __align__(16) f32x4 pA[4][64];      // phase-A k-half-1 partials
  __shared__ __align__(16) f32x4 pB[6][64];      // phase-B k-quarter 1..3 partials

  // --- load the block's entire W slice into LDS (12 x uint4 per thread) ---
#pragma unroll
  for (int it = 0; it < 12; ++it) {
    int i = it * 512 + t;                  // 0..6143
    int lane = i & 63;
    int kt   = (i >> 6) & 15;
    int rtl  = (i >> 10) & 1;
    int g    = i >> 11;                    // 0..2
    uint4 v = WF[((size_t)(g * 32 + q * 2 + rtl) * 16 + kt) * 64 + lane];
    *(uint4*)&whlds[(((g * 2 + rtl) * 16 + kt) * 64 + lane) * 8] = v;
  }

  // --- init h: f32 master regs (phase-B owners) + f16 hbuf (all) ---
  f32x4 hold = *(const f32x4*)(h0 + (size_t)bglob * 512 + jB);
  {
    int b = t >> 5, j = (t & 31) * 16;
    const float4* s = (const float4*)(h0 + (size_t)(c * 16 + b) * 512 + j);
    float4 v0 = s[0], v1 = s[1], v2 = s[2], v3 = s[3];
    uint4 o0, o1;
    o0.x = pk2h(v0.x, v0.y); o0.y = pk2h(v0.z, v0.w);
    o0.z = pk2h(v1.x, v1.y); o0.w = pk2h(v1.z, v1.w);
    o1.x = pk2h(v2.x, v2.y); o1.y = pk2h(v2.z, v2.w);
    o1.z = pk2h(v3.x, v3.y); o1.w = pk2h(v3.z, v3.w);
    uint4* d = (uint4*)&hbuf[b * 520 + j];
    d[0] = o0; d[1] = o1;
  }
  __syncthreads();

  const u16* PpA = P + (size_t)gA * PJ_GATE + (size_t)bglob * 512 + jA;  // khA==0
  const u16* PpH = P + 2 * PJ_GATE + (size_t)bglob * 512 + jB;           // kqB==0

  // poll mapping: b = t>>5, j = (t&31)*16, 8 contiguous u64
  const int bR = t >> 5;
  const int jR = (t & 31) * 16;
  const int CL  = 16 * 512;               // u32 per cluster
  const int PAR = 4 * CL;                 // u32 per parity

  uint2 pgu = *(const uint2*)PpA;         // own-gate P, step 0

  for (int ts = 0; ts < S_; ++ts) {
    const int par = ts & 1;
    const u32 taghi = (u32)(ts + 1) << 16;
    const u64 tp = (u64)taghi | ((u64)taghi << 32);
    u32* RHXp = RHX + par * PAR + c * CL;
    u32* HXp  = HX  + par * PAR + c * CL;

    // prefetch P_h early (used in phase-B combine by kqB==0 waves)
    uint2 phu = *(const uint2*)(PpH + (size_t)ts * 32768);

    // ---- phase A: own gate, own row-tile, own k-half (8 MFMAs) ----
    f32x4 aa = {0.f, 0.f, 0.f, 0.f};
#pragma unroll
    for (int i = 0; i < 8; ++i) {
      int kt = khA * 8 + i;
      f16x8 hv = *(const f16x8*)&hbuf[bq * 520 + kt * 32 + g4 * 8];
      f16x8 wv = *(const f16x8*)&whlds[(((gA * 2 + rtA) * 16 + kt) * 64 + l) * 8];
      aa = __builtin_amdgcn_mfma_f32_16x16x32_f16(wv, hv, aa, 0, 0, 0);
    }
    if (khA == 1) pA[w >> 1][l] = aa;
    __syncthreads();   // pA staged
    if (khA == 0) {
      f32x4 s = aa + pA[w >> 1][l];
      h2_t pg0 = __builtin_bit_cast(h2_t, pgu.x), pg1 = __builtin_bit_cast(h2_t, pgu.y);
      float v0 = sigmoidf_(s[0] + (float)pg0[0]);
      float v1 = sigmoidf_(s[1] + (float)pg0[1]);
      float v2 = sigmoidf_(s[2] + (float)pg1[0]);
      float v3 = sigmoidf_(s[3] + (float)pg1[1]);
      if (gA == 0) {
        // rh = r * h_old (h_old f16 from hbuf)
        uint2 hAp = *(const uint2*)&hbuf[bq * 520 + jA];
        h2_t hA0 = __builtin_bit_cast(h2_t, hAp.x), hA1 = __builtin_bit_cast(h2_t, hAp.y);
        f32x4 rh = {v0 * (float)hA0[0], v1 * (float)hA0[1],
                    v2 * (float)hA1[0], v3 * (float)hA1[1]};
        pub4(RHXp + bq * 512 + jA, taghi, rh);
      } else {
        int lr = rtA * 16 + g4 * 4;
        zbuf[lr + 0][bq] = v0;
        zbuf[lr + 1][bq] = v1;
        zbuf[lr + 2][bq] = v2;
        zbuf[lr + 3][bq] = v3;
      }
    }
    // prefetch next step's own-gate P (overlaps poll)
    {
      int tsn = (ts < S_ - 1) ? ts + 1 : ts;
      pgu = *(const uint2*)(PpA + (size_t)tsn * 32768);
    }

    // ---- poll rh (all 512 rows, own cluster's batches) -> rhbuf ----
    poll8_to_lds(RHXp + bR * 512 + jR, &rhbuf[bR * 520 + jR], tp);
    __syncthreads();   // rhbuf + zbuf complete

    // ---- phase B: htilde partials, own row-tile, own k-quarter (4 MFMAs) ----
    f32x4 bb = {0.f, 0.f, 0.f, 0.f};
#pragma unroll
    for (int i = 0; i < 4; ++i) {
      int kt = kqB * 4 + i;
      f16x8 rv = *(const f16x8*)&rhbuf[bq * 520 + kt * 32 + g4 * 8];
      f16x8 wv = *(const f16x8*)&whlds[(((2 * 2 + rtB) * 16 + kt) * 64 + l) * 8];
      bb = __builtin_amdgcn_mfma_f32_16x16x32_f16(wv, rv, bb, 0, 0, 0);
    }
    if (kqB != 0) pB[(kqB - 1) * 2 + rtB][l] = bb;
    __syncthreads();   // pB staged

    // ---- combine (kqB==0 waves, i.e. w0/w1): reduce, tanh, gate, publish ----
    if (kqB == 0) {
      f32x4 s = bb + pB[rtB][l] + pB[2 + rtB][l] + pB[4 + rtB][l];
      h2_t ph0 = __builtin_bit_cast(h2_t, phu.x), ph1 = __builtin_bit_cast(h2_t, phu.y);
      float ht0 = tanhf_(s[0] + (float)ph0[0]);
      float ht1 = tanhf_(s[1] + (float)ph0[1]);
      float ht2 = tanhf_(s[2] + (float)ph1[0]);
      float ht3 = tanhf_(s[3] + (float)ph1[1]);
      int lr = rtB * 16 + g4 * 4;
      float z0 = zbuf[lr + 0][bq], z1 = zbuf[lr + 1][bq];
      float z2 = zbuf[lr + 2][bq], z3 = zbuf[lr + 3][bq];
      f32x4 hn;
      hn[0] = z0 * ht0 + (1.f - z0) * hold[0];
      hn[1] = z1 * ht1 + (1.f - z1) * hold[1];
      hn[2] = z2 * ht2 + (1.f - z2) * hold[2];
      hn[3] = z3 * ht3 + (1.f - z3) * hold[3];
      hold = hn;
      pub4(HXp + bq * 512 + jB, taghi, hn);
      __builtin_nontemporal_store(hn,
          (f32x4*)(y + (size_t)bglob * 262144 + (size_t)ts * 512 + jB));
    }

    // ---- poll h (all 512 rows) -> hbuf ----
    poll8_to_lds(HXp + bR * 512 + jR, &hbuf[bR * 520 + jR], tp);
    __syncthreads();   // hbuf ready for next phase A
  }

  if (kqB == 0)
    *(f32x4*)(hlast + (size_t)bglob * 512 + jB) = hold;
}

// ---------- host ----------
extern "C" void kernel_launch(void* const* d_in, const int* in_sizes, int n_in,
                              void* d_out, int out_size, void* d_ws, size_t ws_size,
                              hipStream_t stream) {
  const float* x  = (const float*)d_in[0];
  const float* h0 = (const float*)d_in[1];
  const float* Wr = (const float*)d_in[2];
  const float* br = (const float*)d_in[3];
  const float* Wz = (const float*)d_in[4];
  const float* bz = (const float*)d_in[5];
  const float* Wh = (const float*)d_in[6];
  const float* bh = (const float*)d_in[7];

  char* ws = (char*)d_ws;
  // layout: WF 1.5MB @0 | P 96MB @2MB | RHX 256KB | HX 256KB
  uint4* WF  = (uint4*)ws;
  u16*   P   = (u16*)(ws + 2097152);
  u32*   RHX = (u32*)(ws + 102760448);
  u32*   HX  = (u32*)(ws + 103022592);

  float* y     = (float*)d_out;
  float* hlast = y + (size_t)B_ * S_ * H_;

  (void)hipMemsetAsync(ws + 102760448, 0, 524288, stream);   // clear exchange tags
  k_convert_w<<<dim3(128, 3), dim3(256), 0, stream>>>(Wr, Wz, Wh, WF);
  k_proj_gemm<<<dim3(512, 8, 3), dim3(256), 0, stream>>>(x, Wr, Wz, Wh, br, bz, bh, P);
  k_gru_scan<<<dim3(64), dim3(512), 0, stream>>>(h0, P, WF, RHX, HX, y, hlast);
}

// Round 13
// 4622.065 us; speedup vs baseline: 1.3180x; 1.3180x over previous
//
#include <hip/hip_runtime.h>

#define B_ 64
#define S_ 512
#define H_ 512

typedef unsigned short u16;
typedef unsigned int   u32;
typedef unsigned long long u64;

typedef __attribute__((ext_vector_type(8))) short    bf16x8;
typedef __attribute__((ext_vector_type(8))) _Float16 f16x8;
typedef __attribute__((ext_vector_type(4))) float    f32x4;
typedef __attribute__((ext_vector_type(2))) _Float16 h2_t;

#define PJ_GATE ((size_t)512 * 64 * 512)   // P stride per gate: [512 ts][64 b][512 j]

// ---------- helpers ----------
__device__ inline u16 f2bf(float f) {            // RNE fp32 -> bf16 bits
  u32 u = __builtin_bit_cast(u32, f);
  u32 r = (u + 0x7fffu + ((u >> 16) & 1u)) >> 16;
  return (u16)r;
}
__device__ inline u32 pkbf2(float a, float b) {
  return (u32)f2bf(a) | ((u32)f2bf(b) << 16);
}
__device__ inline u16 f2h(float a) {
  _Float16 x = (_Float16)a;
  return __builtin_bit_cast(u16, x);
}
__device__ inline u32 pk2h(float a, float b) {
  return (u32)f2h(a) | ((u32)f2h(b) << 16);
}
__device__ inline float sigmoidf_(float x) { return 1.f / (1.f + __expf(-x)); }
__device__ inline float tanhf_(float x) {
  float e = __expf(-2.f * fabsf(x));
  float t = (1.f - e) / (1.f + e);
  return copysignf(t, x);
}
__device__ inline void xstore64(u64* p, u64 v) {
  __hip_atomic_store(p, v, __ATOMIC_RELAXED, __HIP_MEMORY_SCOPE_AGENT);
}
__device__ inline u64 xload(const u64* p) {
  return __hip_atomic_load(p, __ATOMIC_RELAXED, __HIP_MEMORY_SCOPE_AGENT);
}
// u16 index of h element (batch b, row j) in MFMA-fragment-native LDS layout:
// fragment (kt=j>>5, lane=b+(((j&31)>>3)<<4), e=j&7) at kt*512 + lane*8 + e.
__device__ inline int fragAddr(int j, int b) {
  return ((j >> 5) << 9) + ((b + (((j & 31) >> 3) << 4)) << 3) + (j & 7);
}

// ---------- kernel 1: W recurrent half -> f16 MFMA A-fragments ----------
// WF[g][rt][kt][lane] (uint4): 8 f16 = W_g[rt*16+(lane&15)][512 + kt*32 + (lane>>4)*8 + 0..7]
__global__ void k_convert_w(const float* __restrict__ Wr, const float* __restrict__ Wz,
                            const float* __restrict__ Wh, uint4* __restrict__ WF) {
  int g = blockIdx.y;
  const float* Ws = (g == 0) ? Wr : ((g == 1) ? Wz : Wh);
  int i = blockIdx.x * 256 + threadIdx.x;   // 0..32767
  int lane = i & 63;
  int kt   = (i >> 6) & 15;
  int rt   = i >> 10;                       // 0..31
  int row  = rt * 16 + (lane & 15);
  int col  = 512 + kt * 32 + (lane >> 4) * 8;
  const float* src = Ws + (size_t)row * 1024 + col;
  float4 a = *(const float4*)src;
  float4 b = *(const float4*)(src + 4);
  uint4 o;
  o.x = pk2h(a.x, a.y); o.y = pk2h(a.z, a.w);
  o.z = pk2h(b.x, b.y); o.w = pk2h(b.z, b.w);
  WF[((size_t)(g * 32 + rt) * 16 + kt) * 64 + lane] = o;
}

// ---------- kernel 2: projection GEMM (f32 in, bf16 MFMA, f16 out) ----------
__global__ __launch_bounds__(256) void k_proj_gemm(
    const float* __restrict__ x,
    const float* __restrict__ Wr, const float* __restrict__ Wz, const float* __restrict__ Wh,
    const float* __restrict__ br, const float* __restrict__ bz, const float* __restrict__ bh,
    u16* __restrict__ P)
{
  const int g  = blockIdx.z;
  const int bm = blockIdx.x * 64;
  const int bn = blockIdx.y * 64;
  const float* Ws = (g == 0) ? Wr : ((g == 1) ? Wz : Wh);
  __shared__ __align__(16) u16 As[64][32];
  __shared__ __align__(16) u16 Bs[64][32];
  const int tid  = threadIdx.x;
  const int lane = tid & 63;
  const int wm   = (tid >> 6) >> 1;
  const int wn   = (tid >> 6) & 1;
  const int srow = tid >> 2;
  const int scol = (tid & 3) * 8;

  f32x4 zero4 = {0.f, 0.f, 0.f, 0.f};
  f32x4 acc[2][2];
  acc[0][0] = zero4; acc[0][1] = zero4; acc[1][0] = zero4; acc[1][1] = zero4;

  for (int k0 = 0; k0 < 512; k0 += 32) {
    __syncthreads();
    {
      const float* xs = x + (size_t)(bm + srow) * 512 + k0 + scol;
      float4 a = *(const float4*)xs, b = *(const float4*)(xs + 4);
      uint4 av; av.x = pkbf2(a.x, a.y); av.y = pkbf2(a.z, a.w);
      av.z = pkbf2(b.x, b.y); av.w = pkbf2(b.z, b.w);
      *(uint4*)(&As[srow][scol]) = av;
      const float* wsrc = Ws + (size_t)(bn + srow) * 1024 + k0 + scol;
      float4 c = *(const float4*)wsrc, d = *(const float4*)(wsrc + 4);
      uint4 bv; bv.x = pkbf2(c.x, c.y); bv.y = pkbf2(c.z, c.w);
      bv.z = pkbf2(d.x, d.y); bv.w = pkbf2(d.z, d.w);
      *(uint4*)(&Bs[srow][scol]) = bv;
    }
    __syncthreads();
#pragma unroll
    for (int mi = 0; mi < 2; ++mi) {
      bf16x8 a = *(const bf16x8*)(&As[wm * 32 + mi * 16 + (lane & 15)][(lane >> 4) * 8]);
#pragma unroll
      for (int ni = 0; ni < 2; ++ni) {
        bf16x8 b = *(const bf16x8*)(&Bs[wn * 32 + ni * 16 + (lane & 15)][(lane >> 4) * 8]);
        acc[mi][ni] = __builtin_amdgcn_mfma_f32_16x16x32_bf16(a, b, acc[mi][ni], 0, 0, 0);
      }
    }
  }
  const float* bias = (g == 0) ? br : ((g == 1) ? bz : bh);
#pragma unroll
  for (int mi = 0; mi < 2; ++mi)
#pragma unroll
    for (int ni = 0; ni < 2; ++ni) {
      int col  = bn + wn * 32 + ni * 16 + (lane & 15);
      float bv = bias[col];
#pragma unroll
      for (int r = 0; r < 4; ++r) {
        int row = bm + wm * 32 + mi * 16 + (lane >> 4) * 4 + r;
        int bb = row >> 9, ss = row & 511;
        float v = acc[mi][ni][r] + bv;
        P[((size_t)g * 512 + ss) * (64 * 512) + (size_t)bb * 512 + col] =
            __builtin_bit_cast(u16, (_Float16)v);
      }
    }
}

// ---------- kernel 3: GRU scan — round-5 structure + conflict-free LDS +
//             early rh publish (r-gate before z-gate) ----------
// 16 blocks x 512 thr. cluster c = blockIdx>>2 owns batches 16c..16c+15;
// block q = blockIdx&3 owns rows [128q,128q+128) of all 3 gates; W streamed.
// hbuf holds h/rh in MFMA-fragment-native layout -> ds_read_b128 lane-linear.
// Exchange: tagged u32 slots, relaxed agent atomics, parity dbuf, max skew 1.
__global__ __launch_bounds__(512, 2) void k_gru_scan(
    const float* __restrict__ h0,
    const u16*  __restrict__ P,       // [3][512 ts][64 b][512 j] f16
    const uint4* __restrict__ WF,     // fragment-packed recurrent W (f16)
    u32* __restrict__ RHX,            // [2 par][4 c][16 b][512 k] tagged r*h
    u32* __restrict__ HX,             // [2 par][4 c][16 b][512 j] tagged h
    float* __restrict__ y,
    float* __restrict__ hlast)
{
  const int q = blockIdx.x & 3;
  const int c = blockIdx.x >> 2;
  const int t = threadIdx.x;
  const int w = t >> 6;          // wave 0..7
  const int l = t & 63;
  const int bq = l & 15;         // batch within cluster
  const int g4 = l >> 4;         // 0..3
  const int bglob = c * 16 + bq;
  const int rt  = q * 8 + w;
  const int j0A = q * 128 + w * 16 + g4 * 4;   // own rows (4)
  const int ownA = fragAddr(j0A, bq);          // u16 idx of own 4 elems (uint2)

  __shared__ __align__(16) u16 hbuf[16 * 512];  // 16 KB, fragment-native, reused

  // --- W fragments (compiler decides residency/stream — round-5 behavior) ---
  f16x8 wr[16], wz[16], wh[16];
#pragma unroll
  for (int kt = 0; kt < 16; ++kt) {
    wr[kt] = __builtin_bit_cast(f16x8, WF[((size_t)(0 * 32 + rt) * 16 + kt) * 64 + l]);
    wz[kt] = __builtin_bit_cast(f16x8, WF[((size_t)(1 * 32 + rt) * 16 + kt) * 64 + l]);
    wh[kt] = __builtin_bit_cast(f16x8, WF[((size_t)(2 * 32 + rt) * 16 + kt) * 64 + l]);
  }

  // --- init h: f32 own-rows reg + fragment-native hbuf ---
  f32x4 hold = *(const f32x4*)(h0 + (size_t)bglob * 512 + j0A);
  {
    int b = t >> 5, j = (t & 31) * 16;
    const float4* s = (const float4*)(h0 + (size_t)(c * 16 + b) * 512 + j);
    float4 v0 = s[0], v1 = s[1], v2 = s[2], v3 = s[3];
    uint4 o0, o1;
    o0.x = pk2h(v0.x, v0.y); o0.y = pk2h(v0.z, v0.w);
    o0.z = pk2h(v1.x, v1.y); o0.w = pk2h(v1.z, v1.w);
    o1.x = pk2h(v2.x, v2.y); o1.y = pk2h(v2.z, v2.w);
    o1.z = pk2h(v3.x, v3.y); o1.w = pk2h(v3.z, v3.w);
    *(uint4*)&hbuf[fragAddr(j, b)]     = o0;
    *(uint4*)&hbuf[fragAddr(j + 8, b)] = o1;
  }
  __syncthreads();

  const u16* Ppr = P + (size_t)bglob * 512 + j0A;
  const u16* Ppz = P + PJ_GATE + (size_t)bglob * 512 + j0A;
  const u16* Pph = P + 2 * PJ_GATE + (size_t)bglob * 512 + j0A;

  // poll-reader mapping: bR = t>>5 (0..15), kR = (t&31)*4; 3 remote quarters
  const int bR = t >> 5;
  const int kR = (t & 31) * 4;
  const int k1 = ((q + 1) & 3) * 128 + kR;
  const int k2 = ((q + 2) & 3) * 128 + kR;
  const int k3 = ((q + 3) & 3) * 128 + kR;
  const int a1 = fragAddr(k1, bR);
  const int a2 = fragAddr(k2, bR);
  const int a3 = fragAddr(k3, bR);
  const int CL  = 16 * 512;                // u32 per cluster
  const int PAR = 4 * CL;                  // u32 per parity

  uint2 pru = *(const uint2*)Ppr;
  uint2 pzu = *(const uint2*)Ppz;

#define POLL_INTO_HBUF(Xp)                                                      \
  {                                                                             \
    const u64* p1 = (const u64*)((Xp) + bR * 512 + k1);                         \
    const u64* p2 = (const u64*)((Xp) + bR * 512 + k2);                         \
    const u64* p3 = (const u64*)((Xp) + bR * 512 + k3);                         \
    u64 A1 = xload(p1), B1 = xload(p1 + 1);                                     \
    u64 A2 = xload(p2), B2 = xload(p2 + 1);                                     \
    u64 A3 = xload(p3), B3 = xload(p3 + 1);                                     \
    while (((A1 ^ tp) & TMASK) != 0ull) { __builtin_amdgcn_s_sleep(1); A1 = xload(p1); } \
    while (((B1 ^ tp) & TMASK) != 0ull) { __builtin_amdgcn_s_sleep(1); B1 = xload(p1 + 1); } \
    while (((A2 ^ tp) & TMASK) != 0ull) { __builtin_amdgcn_s_sleep(1); A2 = xload(p2); } \
    while (((B2 ^ tp) & TMASK) != 0ull) { __builtin_amdgcn_s_sleep(1); B2 = xload(p2 + 1); } \
    while (((A3 ^ tp) & TMASK) != 0ull) { __builtin_amdgcn_s_sleep(1); A3 = xload(p3); } \
    while (((B3 ^ tp) & TMASK) != 0ull) { __builtin_amdgcn_s_sleep(1); B3 = xload(p3 + 1); } \
    uint2 w1, w2, w3;                                                           \
    w1.x = (u32)(A1 & 0xffffu) | (((u32)(A1 >> 32) & 0xffffu) << 16);           \
    w1.y = (u32)(B1 & 0xffffu) | (((u32)(B1 >> 32) & 0xffffu) << 16);           \
    w2.x = (u32)(A2 & 0xffffu) | (((u32)(A2 >> 32) & 0xffffu) << 16);           \
    w2.y = (u32)(B2 & 0xffffu) | (((u32)(B2 >> 32) & 0xffffu) << 16);           \
    w3.x = (u32)(A3 & 0xffffu) | (((u32)(A3 >> 32) & 0xffffu) << 16);           \
    w3.y = (u32)(B3 & 0xffffu) | (((u32)(B3 >> 32) & 0xffffu) << 16);           \
    *(uint2*)&hbuf[a1] = w1;                                                    \
    *(uint2*)&hbuf[a2] = w2;                                                    \
    *(uint2*)&hbuf[a3] = w3;                                                    \
  }

  const u64 TMASK = 0xffff0000ffff0000ull;

  for (int ts = 0; ts < S_; ++ts) {
    const int par = ts & 1;
    const u32 tag = (u32)(ts + 1);
    const u64 tp  = ((u64)tag << 16) | ((u64)tag << 48);
    u32* RHXp = RHX + par * PAR + c * CL;
    u32* HXp  = HX  + par * PAR + c * CL;

    // prefetch P_h for this step (used in phase B)
    uint2 phu = *(const uint2*)(Pph + (size_t)ts * 32768);

    // ---- phase A1: r gate (16 MFMAs), publish rh EARLY ----
    f32x4 ar = {0.f, 0.f, 0.f, 0.f};
#pragma unroll
    for (int kt = 0; kt < 16; ++kt) {
      f16x8 hv = *(const f16x8*)&hbuf[(kt << 9) + (l << 3)];
      ar = __builtin_amdgcn_mfma_f32_16x16x32_f16(wr[kt], hv, ar, 0, 0, 0);
    }
    h2_t pr0 = __builtin_bit_cast(h2_t, pru.x), pr1 = __builtin_bit_cast(h2_t, pru.y);
    float rr0 = sigmoidf_(ar[0] + (float)pr0[0]);
    float rr1 = sigmoidf_(ar[1] + (float)pr0[1]);
    float rr2 = sigmoidf_(ar[2] + (float)pr1[0]);
    float rr3 = sigmoidf_(ar[3] + (float)pr1[1]);
    u16 rh0 = f2h(rr0 * hold[0]), rh1 = f2h(rr1 * hold[1]);
    u16 rh2 = f2h(rr2 * hold[2]), rh3 = f2h(rr3 * hold[3]);
    {
      u64 v01 = (u64)((tag << 16) | rh0) | ((u64)((tag << 16) | rh1) << 32);
      u64 v23 = (u64)((tag << 16) | rh2) | ((u64)((tag << 16) | rh3) << 32);
      xstore64((u64*)(RHXp + bq * 512 + j0A), v01);
      xstore64((u64*)(RHXp + bq * 512 + j0A + 2), v23);
    }

    // ---- phase A2: z gate (16 MFMAs) while rh propagates ----
    f32x4 az = {0.f, 0.f, 0.f, 0.f};
#pragma unroll
    for (int kt = 0; kt < 16; ++kt) {
      f16x8 hv = *(const f16x8*)&hbuf[(kt << 9) + (l << 3)];
      az = __builtin_amdgcn_mfma_f32_16x16x32_f16(wz[kt], hv, az, 0, 0, 0);
    }
    h2_t pz0 = __builtin_bit_cast(h2_t, pzu.x), pz1 = __builtin_bit_cast(h2_t, pzu.y);
    float zz0 = sigmoidf_(az[0] + (float)pz0[0]);
    float zz1 = sigmoidf_(az[1] + (float)pz0[1]);
    float zz2 = sigmoidf_(az[2] + (float)pz1[0]);
    float zz3 = sigmoidf_(az[3] + (float)pz1[1]);

    __syncthreads();   // everyone done reading hbuf as h
    *(uint2*)&hbuf[ownA] =
        uint2{(u32)rh0 | ((u32)rh1 << 16), (u32)rh2 | ((u32)rh3 << 16)};
    POLL_INTO_HBUF(RHXp)
    __syncthreads();   // rh complete in hbuf

    // ---- phase B: htilde own rows (16 MFMAs); update h ----
    f32x4 ah = {0.f, 0.f, 0.f, 0.f};
#pragma unroll
    for (int kt = 0; kt < 16; ++kt) {
      f16x8 rv = *(const f16x8*)&hbuf[(kt << 9) + (l << 3)];
      ah = __builtin_amdgcn_mfma_f32_16x16x32_f16(wh[kt], rv, ah, 0, 0, 0);
    }
    h2_t ph0 = __builtin_bit_cast(h2_t, phu.x), ph1 = __builtin_bit_cast(h2_t, phu.y);
    float ht0 = tanhf_(ah[0] + (float)ph0[0]);
    float ht1 = tanhf_(ah[1] + (float)ph0[1]);
    float ht2 = tanhf_(ah[2] + (float)ph1[0]);
    float ht3 = tanhf_(ah[3] + (float)ph1[1]);
    f32x4 hn;
    hn[0] = zz0 * ht0 + (1.f - zz0) * hold[0];
    hn[1] = zz1 * ht1 + (1.f - zz1) * hold[1];
    hn[2] = zz2 * ht2 + (1.f - zz2) * hold[2];
    hn[3] = zz3 * ht3 + (1.f - zz3) * hold[3];
    hold = hn;
    u16 h0b = f2h(hn[0]), h1b = f2h(hn[1]), h2b = f2h(hn[2]), h3b = f2h(hn[3]);
    {
      u64 v01 = (u64)((tag << 16) | h0b) | ((u64)((tag << 16) | h1b) << 32);
      u64 v23 = (u64)((tag << 16) | h2b) | ((u64)((tag << 16) | h3b) << 32);
      xstore64((u64*)(HXp + bq * 512 + j0A), v01);
      xstore64((u64*)(HXp + bq * 512 + j0A + 2), v23);
    }
    __builtin_nontemporal_store(hn,
        (f32x4*)(y + (size_t)bglob * 262144 + (size_t)ts * 512 + j0A));

    // prefetch next step's P_r/P_z while publish propagates
    {
      int tsn = (ts < S_ - 1) ? ts + 1 : ts;
      pru = *(const uint2*)(Ppr + (size_t)tsn * 32768);
      pzu = *(const uint2*)(Ppz + (size_t)tsn * 32768);
    }

    __syncthreads();   // everyone done reading hbuf as rh
    *(uint2*)&hbuf[ownA] =
        uint2{(u32)h0b | ((u32)h1b << 16), (u32)h2b | ((u32)h3b << 16)};
    POLL_INTO_HBUF(HXp)
    __syncthreads();   // h complete in hbuf
  }

  *(f32x4*)(hlast + (size_t)bglob * 512 + j0A) = hold;
}

// ---------- host ----------
extern "C" void kernel_launch(void* const* d_in, const int* in_sizes, int n_in,
                              void* d_out, int out_size, void* d_ws, size_t ws_size,
                              hipStream_t stream) {
  const float* x  = (const float*)d_in[0];
  const float* h0 = (const float*)d_in[1];
  const float* Wr = (const float*)d_in[2];
  const float* br = (const float*)d_in[3];
  const float* Wz = (const float*)d_in[4];
  const float* bz = (const float*)d_in[5];
  const float* Wh = (const float*)d_in[6];
  const float* bh = (const float*)d_in[7];

  char* ws = (char*)d_ws;
  // layout: WF 1.5MB @0 | P 96MB @2MB | RHX 256KB | HX 256KB
  uint4* WF  = (uint4*)ws;
  u16*   P   = (u16*)(ws + 2097152);
  u32*   RHX = (u32*)(ws + 102760448);
  u32*   HX  = (u32*)(ws + 103022592);

  float* y     = (float*)d_out;
  float* hlast = y + (size_t)B_ * S_ * H_;

  (void)hipMemsetAsync(ws + 102760448, 0, 524288, stream);   // clear exchange tags
  k_convert_w<<<dim3(128, 3), dim3(256), 0, stream>>>(Wr, Wz, Wh, WF);
  k_proj_gemm<<<dim3(512, 8, 3), dim3(256), 0, stream>>>(x, Wr, Wz, Wh, br, bz, bh, P);
  k_gru_scan<<<dim3(16), dim3(512), 0, stream>>>(h0, P, WF, RHX, HX, y, hlast);
}

// Round 14
// 4459.144 us; speedup vs baseline: 1.3662x; 1.0365x over previous
//
#include <hip/hip_runtime.h>

#define B_ 64
#define S_ 512
#define H_ 512

typedef unsigned short u16;
typedef unsigned int   u32;
typedef unsigned long long u64;

typedef __attribute__((ext_vector_type(8))) short    bf16x8;
typedef __attribute__((ext_vector_type(8))) _Float16 f16x8;
typedef __attribute__((ext_vector_type(4))) float    f32x4;
typedef __attribute__((ext_vector_type(2))) _Float16 h2_t;

#define PJ_GATE ((size_t)512 * 64 * 512)   // P stride per gate: [512 ts][64 b][512 j]
#define TMASK 0xffff0000ffff0000ull

// ---------- helpers ----------
__device__ inline u16 f2bf(float f) {            // RNE fp32 -> bf16 bits
  u32 u = __builtin_bit_cast(u32, f);
  u32 r = (u + 0x7fffu + ((u >> 16) & 1u)) >> 16;
  return (u16)r;
}
__device__ inline u32 pkbf2(float a, float b) {
  return (u32)f2bf(a) | ((u32)f2bf(b) << 16);
}
__device__ inline u16 f2h(float a) {
  _Float16 x = (_Float16)a;
  return __builtin_bit_cast(u16, x);
}
__device__ inline u32 pk2h(float a, float b) {
  return (u32)f2h(a) | ((u32)f2h(b) << 16);
}
__device__ inline float sigmoidf_(float x) { return 1.f / (1.f + __expf(-x)); }
__device__ inline float tanhf_(float x) {
  float e = __expf(-2.f * fabsf(x));
  float t = (1.f - e) / (1.f + e);
  return copysignf(t, x);
}
__device__ inline void xstore64(u64* p, u64 v) {
  __hip_atomic_store(p, v, __ATOMIC_RELAXED, __HIP_MEMORY_SCOPE_AGENT);
}
__device__ inline u64 xload(const u64* p) {
  return __hip_atomic_load(p, __ATOMIC_RELAXED, __HIP_MEMORY_SCOPE_AGENT);
}
__device__ inline u32 pklo(u64 v) {   // [tag|f16][tag|f16] -> f16|f16<<16
  return (u32)(v & 0xffffu) | (((u32)(v >> 32)) << 16);
}
// u16 index of h element (batch b, row j) in MFMA-fragment-native LDS layout:
// frag kt=j>>5 at kt*512; within: lane = b + 16*((j>>3)&3), elem e = j&7.
__device__ inline int fragAddr(int j, int b) {
  return ((j >> 5) << 9) + ((b + (((j >> 3) & 3) << 4)) << 3) + (j & 7);
}

// ---------- kernel 1: W recurrent half -> f16 MFMA A-fragments ----------
// WF[g][rt][kt][lane] (uint4): 8 f16 = W_g[rt*16+(lane&15)][512 + kt*32 + (lane>>4)*8 + 0..7]
__global__ void k_convert_w(const float* __restrict__ Wr, const float* __restrict__ Wz,
                            const float* __restrict__ Wh, uint4* __restrict__ WF) {
  int g = blockIdx.y;
  const float* Ws = (g == 0) ? Wr : ((g == 1) ? Wz : Wh);
  int i = blockIdx.x * 256 + threadIdx.x;   // 0..32767
  int lane = i & 63;
  int kt   = (i >> 6) & 15;
  int rt   = i >> 10;                       // 0..31
  int row  = rt * 16 + (lane & 15);
  int col  = 512 + kt * 32 + (lane >> 4) * 8;
  const float* src = Ws + (size_t)row * 1024 + col;
  float4 a = *(const float4*)src;
  float4 b = *(const float4*)(src + 4);
  uint4 o;
  o.x = pk2h(a.x, a.y); o.y = pk2h(a.z, a.w);
  o.z = pk2h(b.x, b.y); o.w = pk2h(b.z, b.w);
  WF[((size_t)(g * 32 + rt) * 16 + kt) * 64 + lane] = o;
}

// ---------- kernel 2: projection GEMM (f32 in, bf16 MFMA, f16 out) ----------
__global__ __launch_bounds__(256) void k_proj_gemm(
    const float* __restrict__ x,
    const float* __restrict__ Wr, const float* __restrict__ Wz, const float* __restrict__ Wh,
    const float* __restrict__ br, const float* __restrict__ bz, const float* __restrict__ bh,
    u16* __restrict__ P)
{
  const int g  = blockIdx.z;
  const int bm = blockIdx.x * 64;
  const int bn = blockIdx.y * 64;
  const float* Ws = (g == 0) ? Wr : ((g == 1) ? Wz : Wh);
  __shared__ __align__(16) u16 As[64][32];
  __shared__ __align__(16) u16 Bs[64][32];
  const int tid  = threadIdx.x;
  const int lane = tid & 63;
  const int wm   = (tid >> 6) >> 1;
  const int wn   = (tid >> 6) & 1;
  const int srow = tid >> 2;
  const int scol = (tid & 3) * 8;

  f32x4 zero4 = {0.f, 0.f, 0.f, 0.f};
  f32x4 acc[2][2];
  acc[0][0] = zero4; acc[0][1] = zero4; acc[1][0] = zero4; acc[1][1] = zero4;

  for (int k0 = 0; k0 < 512; k0 += 32) {
    __syncthreads();
    {
      const float* xs = x + (size_t)(bm + srow) * 512 + k0 + scol;
      float4 a = *(const float4*)xs, b = *(const float4*)(xs + 4);
      uint4 av; av.x = pkbf2(a.x, a.y); av.y = pkbf2(a.z, a.w);
      av.z = pkbf2(b.x, b.y); av.w = pkbf2(b.z, b.w);
      *(uint4*)(&As[srow][scol]) = av;
      const float* wsrc = Ws + (size_t)(bn + srow) * 1024 + k0 + scol;
      float4 c = *(const float4*)wsrc, d = *(const float4*)(wsrc + 4);
      uint4 bv; bv.x = pkbf2(c.x, c.y); bv.y = pkbf2(c.z, c.w);
      bv.z = pkbf2(d.x, d.y); bv.w = pkbf2(d.z, d.w);
      *(uint4*)(&Bs[srow][scol]) = bv;
    }
    __syncthreads();
#pragma unroll
    for (int mi = 0; mi < 2; ++mi) {
      bf16x8 a = *(const bf16x8*)(&As[wm * 32 + mi * 16 + (lane & 15)][(lane >> 4) * 8]);
#pragma unroll
      for (int ni = 0; ni < 2; ++ni) {
        bf16x8 b = *(const bf16x8*)(&Bs[wn * 32 + ni * 16 + (lane & 15)][(lane >> 4) * 8]);
        acc[mi][ni] = __builtin_amdgcn_mfma_f32_16x16x32_bf16(a, b, acc[mi][ni], 0, 0, 0);
      }
    }
  }
  const float* bias = (g == 0) ? br : ((g == 1) ? bz : bh);
#pragma unroll
  for (int mi = 0; mi < 2; ++mi)
#pragma unroll
    for (int ni = 0; ni < 2; ++ni) {
      int col  = bn + wn * 32 + ni * 16 + (lane & 15);
      float bv = bias[col];
#pragma unroll
      for (int r = 0; r < 4; ++r) {
        int row = bm + wm * 32 + mi * 16 + (lane >> 4) * 4 + r;
        int bb = row >> 9, ss = row & 511;
        float v = acc[mi][ni][r] + bv;
        P[((size_t)g * 512 + ss) * (64 * 512) + (size_t)bb * 512 + col] =
            __builtin_bit_cast(u16, (_Float16)v);
      }
    }
}

// ---------- kernel 3: GRU scan — 4 waves/block, shared-hv MFMA, lane-linear
//             fragment LDS (reads AND poll-writes conflict-free) ----------
// 16 blocks x 256 thr. cluster c = blockIdx>>2 owns batches 16c..16c+15;
// block q = blockIdx&3 owns rows [128q,128q+128): wave w owns row-tiles
// rt0 = q*8+2w, rt1 = rt0+1 (32 rows). Per kt ONE hv ds_read feeds 4 MFMAs.
// All W streamed from L2 (placement proven neutral, r3 vs r5).
// Exchange: round-5 tagged u32 slots, relaxed agent atomics, parity dbuf.
__global__ __launch_bounds__(256) void k_gru_scan(
    const float* __restrict__ h0,
    const u16*  __restrict__ P,       // [3][512 ts][64 b][512 j] f16
    const uint4* __restrict__ WF,     // fragment-packed recurrent W (f16)
    u32* __restrict__ RHX,            // [2 par][4 c][16 b][512 k] tagged r*h
    u32* __restrict__ HX,             // [2 par][4 c][16 b][512 j] tagged h
    float* __restrict__ y,
    float* __restrict__ hlast)
{
  const int q = blockIdx.x & 3;
  const int c = blockIdx.x >> 2;
  const int t = threadIdx.x;
  const int w = t >> 6;          // wave 0..3
  const int l = t & 63;
  const int bq = l & 15;         // batch within cluster (MFMA col)
  const int g4 = l >> 4;         // 0..3
  const int bglob = c * 16 + bq;
  const int rt0 = q * 8 + 2 * w;
  const int rt1 = rt0 + 1;
  const int jb0 = q * 128 + w * 32 + g4 * 4;        // own rows, sub-tile 0
  const int jb1 = jb0 + 16;                          // sub-tile 1
  const int own0 = fragAddr(jb0, bq);
  const int own1 = fragAddr(jb1, bq);

  __shared__ __align__(16) u16 hbuf[16 * 512];   // 16 KB fragment-native, reused

  // --- W stream bases (L2-resident; compiler pipelines the loads) ---
  const uint4* Wr0 = WF + (size_t)((0 * 32 + rt0) * 16) * 64 + l;
  const uint4* Wr1 = WF + (size_t)((0 * 32 + rt1) * 16) * 64 + l;
  const uint4* Wz0 = WF + (size_t)((1 * 32 + rt0) * 16) * 64 + l;
  const uint4* Wz1 = WF + (size_t)((1 * 32 + rt1) * 16) * 64 + l;
  const uint4* Wh0 = WF + (size_t)((2 * 32 + rt0) * 16) * 64 + l;
  const uint4* Wh1 = WF + (size_t)((2 * 32 + rt1) * 16) * 64 + l;

  // --- init h: f32 own-rows regs + fragment-native hbuf ---
  f32x4 hold0 = *(const f32x4*)(h0 + (size_t)bglob * 512 + jb0);
  f32x4 hold1 = *(const f32x4*)(h0 + (size_t)bglob * 512 + jb1);
  {
    int kt = t >> 4, lp = t & 15;
#pragma unroll
    for (int i = 0; i < 4; ++i) {
      int lane = lp * 4 + i;
      int b = lane & 15, j0 = kt * 32 + (lane >> 4) * 8;
      const float4* s4 = (const float4*)(h0 + (size_t)(c * 16 + b) * 512 + j0);
      float4 va = s4[0], vb = s4[1];
      uint4 o;
      o.x = pk2h(va.x, va.y); o.y = pk2h(va.z, va.w);
      o.z = pk2h(vb.x, vb.y); o.w = pk2h(vb.z, vb.w);
      *(uint4*)&hbuf[kt * 512 + lane * 8] = o;
    }
  }
  __syncthreads();

  const u16* Ppr0 = P + (size_t)bglob * 512 + jb0;
  const u16* Ppr1 = P + (size_t)bglob * 512 + jb1;
  const u16* Ppz0 = P + PJ_GATE + (size_t)bglob * 512 + jb0;
  const u16* Ppz1 = P + PJ_GATE + (size_t)bglob * 512 + jb1;
  const u16* Pph0 = P + 2 * PJ_GATE + (size_t)bglob * 512 + jb0;
  const u16* Pph1 = P + 2 * PJ_GATE + (size_t)bglob * 512 + jb1;

  // poll mapping: per remote quarter p: frag kt = kq*4 + w, frag-lane = l
  // -> rows j0p..j0p+7, batch l&15; 4 contiguous u64; LDS uint4 lane-linear.
  int pofs[3], ldst[3];
#pragma unroll
  for (int p = 0; p < 3; ++p) {
    int ktq = (((q + 1 + p) & 3) * 4 + w);
    int j0p = ktq * 32 + (l >> 4) * 8;
    pofs[p] = (l & 15) * 512 + j0p;      // u32 offset in exchange buffer
    ldst[p] = ktq * 512 + l * 8;         // u16 offset in hbuf
  }
  const int CL  = 16 * 512;              // u32 per cluster
  const int PAR = 4 * CL;                // u32 per parity

#define POLLX(Xp)                                                               \
  {                                                                             \
    u64 v[12];                                                                  \
    _Pragma("unroll")                                                           \
    for (int p = 0; p < 3; ++p) {                                               \
      const u64* pb = (const u64*)((Xp) + pofs[p]);                             \
      v[p * 4 + 0] = xload(pb + 0); v[p * 4 + 1] = xload(pb + 1);               \
      v[p * 4 + 2] = xload(pb + 2); v[p * 4 + 3] = xload(pb + 3);               \
    }                                                                           \
    _Pragma("unroll")                                                           \
    for (int p = 0; p < 3; ++p) {                                               \
      const u64* pb = (const u64*)((Xp) + pofs[p]);                             \
      _Pragma("unroll")                                                         \
      for (int i = 0; i < 4; ++i)                                               \
        while ((v[p * 4 + i] ^ tp) & TMASK) {                                   \
          __builtin_amdgcn_s_sleep(1); v[p * 4 + i] = xload(pb + i);            \
        }                                                                       \
    }                                                                           \
    _Pragma("unroll")                                                           \
    for (int p = 0; p < 3; ++p) {                                               \
      uint4 o;                                                                  \
      o.x = pklo(v[p * 4 + 0]); o.y = pklo(v[p * 4 + 1]);                       \
      o.z = pklo(v[p * 4 + 2]); o.w = pklo(v[p * 4 + 3]);                       \
      *(uint4*)&hbuf[ldst[p]] = o;                                              \
    }                                                                           \
  }

  uint2 pr0u = *(const uint2*)Ppr0, pr1u = *(const uint2*)Ppr1;
  uint2 pz0u = *(const uint2*)Ppz0, pz1u = *(const uint2*)Ppz1;

  for (int ts = 0; ts < S_; ++ts) {
    const int par = ts & 1;
    const u32 taghi = (u32)(ts + 1) << 16;
    const u64 tp = (u64)taghi | ((u64)taghi << 32);
    u32* RHXp = RHX + par * PAR + c * CL;
    u32* HXp  = HX  + par * PAR + c * CL;

    uint2 ph0u = *(const uint2*)(Pph0 + (size_t)ts * 32768);
    uint2 ph1u = *(const uint2*)(Pph1 + (size_t)ts * 32768);

    // ---- phase A: r,z for own 32 rows; ONE hv read per kt -> 4 MFMAs ----
    f32x4 ar0 = {0.f, 0.f, 0.f, 0.f}, ar1 = ar0, az0 = ar0, az1 = ar0;
#pragma unroll
    for (int kt = 0; kt < 16; ++kt) {
      f16x8 hv = *(const f16x8*)&hbuf[(kt << 9) + (l << 3)];
      f16x8 a0 = __builtin_bit_cast(f16x8, Wr0[kt * 64]);
      f16x8 a1 = __builtin_bit_cast(f16x8, Wr1[kt * 64]);
      f16x8 b0 = __builtin_bit_cast(f16x8, Wz0[kt * 64]);
      f16x8 b1 = __builtin_bit_cast(f16x8, Wz1[kt * 64]);
      ar0 = __builtin_amdgcn_mfma_f32_16x16x32_f16(a0, hv, ar0, 0, 0, 0);
      ar1 = __builtin_amdgcn_mfma_f32_16x16x32_f16(a1, hv, ar1, 0, 0, 0);
      az0 = __builtin_amdgcn_mfma_f32_16x16x32_f16(b0, hv, az0, 0, 0, 0);
      az1 = __builtin_amdgcn_mfma_f32_16x16x32_f16(b1, hv, az1, 0, 0, 0);
    }
    h2_t pa, pb_;
    pa = __builtin_bit_cast(h2_t, pr0u.x); pb_ = __builtin_bit_cast(h2_t, pr0u.y);
    float r00 = sigmoidf_(ar0[0] + (float)pa[0]);
    float r01 = sigmoidf_(ar0[1] + (float)pa[1]);
    float r02 = sigmoidf_(ar0[2] + (float)pb_[0]);
    float r03 = sigmoidf_(ar0[3] + (float)pb_[1]);
    pa = __builtin_bit_cast(h2_t, pr1u.x); pb_ = __builtin_bit_cast(h2_t, pr1u.y);
    float r10 = sigmoidf_(ar1[0] + (float)pa[0]);
    float r11 = sigmoidf_(ar1[1] + (float)pa[1]);
    float r12 = sigmoidf_(ar1[2] + (float)pb_[0]);
    float r13 = sigmoidf_(ar1[3] + (float)pb_[1]);
    u16 rhA0 = f2h(r00 * hold0[0]), rhA1 = f2h(r01 * hold0[1]);
    u16 rhA2 = f2h(r02 * hold0[2]), rhA3 = f2h(r03 * hold0[3]);
    u16 rhB0 = f2h(r10 * hold1[0]), rhB1 = f2h(r11 * hold1[1]);
    u16 rhB2 = f2h(r12 * hold1[2]), rhB3 = f2h(r13 * hold1[3]);
    {
      u64* d0 = (u64*)(RHXp + bq * 512 + jb0);
      u64* d1 = (u64*)(RHXp + bq * 512 + jb1);
      xstore64(d0,     (u64)(taghi | rhA0) | ((u64)(taghi | rhA1) << 32));
      xstore64(d0 + 1, (u64)(taghi | rhA2) | ((u64)(taghi | rhA3) << 32));
      xstore64(d1,     (u64)(taghi | rhB0) | ((u64)(taghi | rhB1) << 32));
      xstore64(d1 + 1, (u64)(taghi | rhB2) | ((u64)(taghi | rhB3) << 32));
    }
    pa = __builtin_bit_cast(h2_t, pz0u.x); pb_ = __builtin_bit_cast(h2_t, pz0u.y);
    float z00 = sigmoidf_(az0[0] + (float)pa[0]);
    float z01 = sigmoidf_(az0[1] + (float)pa[1]);
    float z02 = sigmoidf_(az0[2] + (float)pb_[0]);
    float z03 = sigmoidf_(az0[3] + (float)pb_[1]);
    pa = __builtin_bit_cast(h2_t, pz1u.x); pb_ = __builtin_bit_cast(h2_t, pz1u.y);
    float z10 = sigmoidf_(az1[0] + (float)pa[0]);
    float z11 = sigmoidf_(az1[1] + (float)pa[1]);
    float z12 = sigmoidf_(az1[2] + (float)pb_[0]);
    float z13 = sigmoidf_(az1[3] + (float)pb_[1]);
    // prefetch next step's P_r/P_z (overlaps poll)
    {
      int tsn = (ts < S_ - 1) ? ts + 1 : ts;
      pr0u = *(const uint2*)(Ppr0 + (size_t)tsn * 32768);
      pr1u = *(const uint2*)(Ppr1 + (size_t)tsn * 32768);
      pz0u = *(const uint2*)(Ppz0 + (size_t)tsn * 32768);
      pz1u = *(const uint2*)(Ppz1 + (size_t)tsn * 32768);
    }

    __syncthreads();   // all waves done reading hbuf as h
    *(uint2*)&hbuf[own0] =
        uint2{(u32)rhA0 | ((u32)rhA1 << 16), (u32)rhA2 | ((u32)rhA3 << 16)};
    *(uint2*)&hbuf[own1] =
        uint2{(u32)rhB0 | ((u32)rhB1 << 16), (u32)rhB2 | ((u32)rhB3 << 16)};
    POLLX(RHXp)
    __syncthreads();   // rh complete in hbuf

    // ---- phase B: htilde for own 32 rows ----
    f32x4 ah0 = {0.f, 0.f, 0.f, 0.f}, ah1 = ah0;
#pragma unroll
    for (int kt = 0; kt < 16; ++kt) {
      f16x8 rv = *(const f16x8*)&hbuf[(kt << 9) + (l << 3)];
      f16x8 a0 = __builtin_bit_cast(f16x8, Wh0[kt * 64]);
      f16x8 a1 = __builtin_bit_cast(f16x8, Wh1[kt * 64]);
      ah0 = __builtin_amdgcn_mfma_f32_16x16x32_f16(a0, rv, ah0, 0, 0, 0);
      ah1 = __builtin_amdgcn_mfma_f32_16x16x32_f16(a1, rv, ah1, 0, 0, 0);
    }
    pa = __builtin_bit_cast(h2_t, ph0u.x); pb_ = __builtin_bit_cast(h2_t, ph0u.y);
    float t00 = tanhf_(ah0[0] + (float)pa[0]);
    float t01 = tanhf_(ah0[1] + (float)pa[1]);
    float t02 = tanhf_(ah0[2] + (float)pb_[0]);
    float t03 = tanhf_(ah0[3] + (float)pb_[1]);
    pa = __builtin_bit_cast(h2_t, ph1u.x); pb_ = __builtin_bit_cast(h2_t, ph1u.y);
    float t10 = tanhf_(ah1[0] + (float)pa[0]);
    float t11 = tanhf_(ah1[1] + (float)pa[1]);
    float t12 = tanhf_(ah1[2] + (float)pb_[0]);
    float t13 = tanhf_(ah1[3] + (float)pb_[1]);
    f32x4 hn0, hn1;
    hn0[0] = z00 * t00 + (1.f - z00) * hold0[0];
    hn0[1] = z01 * t01 + (1.f - z01) * hold0[1];
    hn0[2] = z02 * t02 + (1.f - z02) * hold0[2];
    hn0[3] = z03 * t03 + (1.f - z03) * hold0[3];
    hn1[0] = z10 * t10 + (1.f - z10) * hold1[0];
    hn1[1] = z11 * t11 + (1.f - z11) * hold1[1];
    hn1[2] = z12 * t12 + (1.f - z12) * hold1[2];
    hn1[3] = z13 * t13 + (1.f - z13) * hold1[3];
    hold0 = hn0; hold1 = hn1;
    u16 hA0 = f2h(hn0[0]), hA1 = f2h(hn0[1]), hA2 = f2h(hn0[2]), hA3 = f2h(hn0[3]);
    u16 hB0 = f2h(hn1[0]), hB1 = f2h(hn1[1]), hB2 = f2h(hn1[2]), hB3 = f2h(hn1[3]);
    {
      u64* d0 = (u64*)(HXp + bq * 512 + jb0);
      u64* d1 = (u64*)(HXp + bq * 512 + jb1);
      xstore64(d0,     (u64)(taghi | hA0) | ((u64)(taghi | hA1) << 32));
      xstore64(d0 + 1, (u64)(taghi | hA2) | ((u64)(taghi | hA3) << 32));
      xstore64(d1,     (u64)(taghi | hB0) | ((u64)(taghi | hB1) << 32));
      xstore64(d1 + 1, (u64)(taghi | hB2) | ((u64)(taghi | hB3) << 32));
    }
    {
      float* yp = y + (size_t)bglob * 262144 + (size_t)ts * 512;
      __builtin_nontemporal_store(hn0, (f32x4*)(yp + jb0));
      __builtin_nontemporal_store(hn1, (f32x4*)(yp + jb1));
    }

    __syncthreads();   // all waves done reading hbuf as rh
    *(uint2*)&hbuf[own0] =
        uint2{(u32)hA0 | ((u32)hA1 << 16), (u32)hA2 | ((u32)hA3 << 16)};
    *(uint2*)&hbuf[own1] =
        uint2{(u32)hB0 | ((u32)hB1 << 16), (u32)hB2 | ((u32)hB3 << 16)};
    POLLX(HXp)
    __syncthreads();   // h complete in hbuf
  }

  *(f32x4*)(hlast + (size_t)bglob * 512 + jb0) = hold0;
  *(f32x4*)(hlast + (size_t)bglob * 512 + jb1) = hold1;
}

// ---------- host ----------
extern "C" void kernel_launch(void* const* d_in, const int* in_sizes, int n_in,
                              void* d_out, int out_size, void* d_ws, size_t ws_size,
                              hipStream_t stream) {
  const float* x  = (const float*)d_in[0];
  const float* h0 = (const float*)d_in[1];
  const float* Wr = (const float*)d_in[2];
  const float* br = (const float*)d_in[3];
  const float* Wz = (const float*)d_in[4];
  const float* bz = (const float*)d_in[5];
  const float* Wh = (const float*)d_in[6];
  const float* bh = (const float*)d_in[7];

  char* ws = (char*)d_ws;
  // layout: WF 1.5MB @0 | P 96MB @2MB | RHX 256KB | HX 256KB
  uint4* WF  = (uint4*)ws;
  u16*   P   = (u16*)(ws + 2097152);
  u32*   RHX = (u32*)(ws + 102760448);
  u32*   HX  = (u32*)(ws + 103022592);

  float* y     = (float*)d_out;
  float* hlast = y + (size_t)B_ * S_ * H_;

  (void)hipMemsetAsync(ws + 102760448, 0, 524288, stream);   // clear exchange tags
  k_convert_w<<<dim3(128, 3), dim3(256), 0, stream>>>(Wr, Wz, Wh, WF);
  k_proj_gemm<<<dim3(512, 8, 3), dim3(256), 0, stream>>>(x, Wr, Wz, Wh, br, bz, bh, P);
  k_gru_scan<<<dim3(16), dim3(256), 0, stream>>>(h0, P, WF, RHX, HX, y, hlast);
}